// Round 1
// baseline (154.654 us; speedup 1.0000x reference)
//
#include <hip/hip_runtime.h>

#define EPS   1e-5f
#define NB    16
#define NS    2048
#define ND    768
#define NK    64
#define NPB   (NS * ND)      /* 1572864 elems per batch */
#define NROWS (NB * NS)      /* 32768 rows */

typedef __attribute__((ext_vector_type(8))) short short8;
typedef __attribute__((ext_vector_type(4))) float f32x4;

static __device__ __forceinline__ short f2bf(float f) {
    unsigned u = __builtin_bit_cast(unsigned, f);
    u += 0x7fffu + ((u >> 16) & 1u);   // round-to-nearest-even
    return (short)(u >> 16);
}

// ---------------------------------------------------------------------------
// Kernel 1 (combined): weight prep + per-batch sum/sumsq reduction.
//   blocks [0,64):    wdp[k][d] = bf16(W_ln[d]*W_down[k][d]); c1[k], c2[k]
//   blocks [64,256):  wub = bf16(W_up) (layout [D][K] unchanged)
//   blocks [256,1280): per-batch {sum, sumsq} via float4 + atomics
// ---------------------------------------------------------------------------
__global__ __launch_bounds__(256) void prep_reduce(
    const float* __restrict__ x, const float* __restrict__ W_up,
    const float* __restrict__ W_down, const float* __restrict__ W_ln,
    const float* __restrict__ b_ln, float* __restrict__ stats,
    float* __restrict__ c1, float* __restrict__ c2,
    short* __restrict__ wdp, short* __restrict__ wub)
{
    const int bid = blockIdx.x, tid = threadIdx.x;
    if (bid < 64) {
        const int k = bid;
        float pc1 = 0.f, pc2 = 0.f;
        for (int d = tid; d < ND; d += 256) {
            float wl = W_ln[d], wd = W_down[k * ND + d], bl = b_ln[d];
            wdp[k * ND + d] = f2bf(wl * wd);
            pc1 += wl * wd;
            pc2 += bl * wd;
        }
        #pragma unroll
        for (int off = 32; off > 0; off >>= 1) {
            pc1 += __shfl_down(pc1, off, 64);
            pc2 += __shfl_down(pc2, off, 64);
        }
        if ((tid & 63) == 0) { atomicAdd(&c1[k], pc1); atomicAdd(&c2[k], pc2); }
    } else if (bid < 256) {
        const int i = (bid - 64) * 256 + tid;   // exactly covers 49152
        wub[i] = f2bf(W_up[i]);
    } else {
        const int cb = bid - 256;               // 0..1023, 64 chunks per batch
        const int b = cb >> 6;
        const int chunk = cb & 63;
        const f32x4* xv = (const f32x4*)(x + (size_t)b * NPB + (size_t)chunk * (NPB / 64));
        float s = 0.f, ss = 0.f;
        #pragma unroll 4
        for (int i = tid; i < NPB / 64 / 4; i += 256) {
            f32x4 v = xv[i];
            s  += v[0] + v[1] + v[2] + v[3];
            ss += v[0]*v[0] + v[1]*v[1] + v[2]*v[2] + v[3]*v[3];
        }
        #pragma unroll
        for (int off = 32; off > 0; off >>= 1) {
            s  += __shfl_down(s, off, 64);
            ss += __shfl_down(ss, off, 64);
        }
        if ((tid & 63) == 0) {
            atomicAdd(&stats[2 * b],     s);
            atomicAdd(&stats[2 * b + 1], ss);
        }
    }
}

// ---------------------------------------------------------------------------
// Kernel 2: fused LN + down-proj + ReLU + up-proj + residual.
// 512 blocks x 256 threads; 4 waves/block; each wave owns 16 rows.
// GEMM1: z[16x64] = bf16(x[16x768]) . wdp^T   (MFMA 16x16x32, 24 k-steps)
// z -> rs*z + kb[col] -> relu -> bf16 -> h_lds (C/D->A layout shuffle)
// GEMM2: out[16x768] = x + h[16x64] . wub^T   (12 col-chunks of 64)
// ---------------------------------------------------------------------------
__global__ __launch_bounds__(256) void fused_main(
    const float* __restrict__ x, const short* __restrict__ wdp,
    const short* __restrict__ wub, const float* __restrict__ c1,
    const float* __restrict__ c2, const float* __restrict__ stats,
    float* __restrict__ out)
{
    __shared__ __align__(16) short h_lds[4][16][64];
    const int tid  = threadIdx.x;
    const int wid  = tid >> 6;
    const int lane = tid & 63;
    const int r    = lane & 15;        // MFMA row (A) / col (B,D)
    const int g    = lane >> 4;        // k-group
    const int row0 = blockIdx.x * 64 + wid * 16;
    const int b    = blockIdx.x >> 5;  // 32 blocks per batch

    const float invN = 1.f / (float)NPB;
    const float mu  = stats[2 * b] * invN;
    const float var = stats[2 * b + 1] * invN - mu * mu;
    const float rs  = rsqrtf(var + EPS);

    // ---- GEMM1: acc[cf] accumulates x-row . wdp[col]  --------------------
    f32x4 acc[4] = {};
    const float* xa = x + (size_t)(row0 + r) * ND;
    #pragma unroll 2
    for (int d0 = 0; d0 < ND; d0 += 32) {
        const int da = d0 + g * 8;
        f32x4 a0 = *(const f32x4*)(xa + da);
        f32x4 a1 = *(const f32x4*)(xa + da + 4);
        short8 af;
        af[0] = f2bf(a0[0]); af[1] = f2bf(a0[1]); af[2] = f2bf(a0[2]); af[3] = f2bf(a0[3]);
        af[4] = f2bf(a1[0]); af[5] = f2bf(a1[1]); af[6] = f2bf(a1[2]); af[7] = f2bf(a1[3]);
        #pragma unroll
        for (int cf = 0; cf < 4; ++cf) {
            short8 bf = *(const short8*)(wdp + (cf * 16 + r) * ND + da);
            acc[cf] = __builtin_amdgcn_mfma_f32_16x16x32_bf16(af, bf, acc[cf], 0, 0, 0);
        }
    }

    // ---- epilogue 1: z = rs*acc + kb[col]; relu; -> h_lds (bf16) ----------
    #pragma unroll
    for (int cf = 0; cf < 4; ++cf) {
        const int col = cf * 16 + r;
        const float kb = c2[col] - rs * mu * c1[col];
        #pragma unroll
        for (int reg = 0; reg < 4; ++reg) {
            float z = fmaf(rs, acc[cf][reg], kb);
            h_lds[wid][g * 4 + reg][col] = f2bf(fmaxf(z, 0.f));
        }
    }
    __syncthreads();

    // ---- GEMM2 A-fragments: full K=64, loaded once ------------------------
    short8 a2_0 = *(const short8*)&h_lds[wid][r][g * 8];
    short8 a2_1 = *(const short8*)&h_lds[wid][r][32 + g * 8];

    const float* xr   = x   + (size_t)row0 * ND;
    float*       outr = out + (size_t)row0 * ND;

    for (int dc = 0; dc < 12; ++dc) {
        f32x4 acc2[4] = {};
        #pragma unroll
        for (int cf = 0; cf < 4; ++cf) {
            const int dcol = dc * 64 + cf * 16 + r;
            short8 b0 = *(const short8*)(wub + dcol * 64 + g * 8);
            short8 b1 = *(const short8*)(wub + dcol * 64 + 32 + g * 8);
            acc2[cf] = __builtin_amdgcn_mfma_f32_16x16x32_bf16(a2_0, b0, acc2[cf], 0, 0, 0);
            acc2[cf] = __builtin_amdgcn_mfma_f32_16x16x32_bf16(a2_1, b1, acc2[cf], 0, 0, 0);
        }
        // ---- epilogue 2: residual add + store ----
        #pragma unroll
        for (int cf = 0; cf < 4; ++cf) {
            #pragma unroll
            for (int reg = 0; reg < 4; ++reg) {
                const int row = g * 4 + reg;
                const int col = dc * 64 + cf * 16 + r;
                outr[(size_t)row * ND + col] = xr[(size_t)row * ND + col] + acc2[cf][reg];
            }
        }
    }
}

// ---------------------------------------------------------------------------
extern "C" void kernel_launch(void* const* d_in, const int* in_sizes, int n_in,
                              void* d_out, int out_size, void* d_ws, size_t ws_size,
                              hipStream_t stream)
{
    const float* x      = (const float*)d_in[0];
    const float* W_up   = (const float*)d_in[1];
    // d_in[2] = b_up   (unused by reference)
    const float* W_down = (const float*)d_in[3];
    // d_in[4] = b_down (unused by reference)
    const float* W_ln   = (const float*)d_in[5];
    const float* b_ln   = (const float*)d_in[6];
    float* out = (float*)d_out;

    char* ws = (char*)d_ws;
    float* stats = (float*)ws;                    // 16 x {sum, sumsq} = 128 B
    float* c1    = (float*)(ws + 128);            // 64 f32
    float* c2    = (float*)(ws + 384);            // 64 f32
    short* wdp   = (short*)(ws + 640);            // bf16 [64][768] = 96 KiB
    short* wub   = (short*)(ws + 640 + 98304);    // bf16 [768][64] = 96 KiB

    hipMemsetAsync(d_ws, 0, 640, stream);
    prep_reduce<<<1280, 256, 0, stream>>>(x, W_up, W_down, W_ln, b_ln,
                                          stats, c1, c2, wdp, wub);
    fused_main<<<512, 256, 0, stream>>>(x, wdp, wub, c1, c2, stats, out);
}

// Round 2
// 85.381 us; speedup vs baseline: 1.8113x; 1.8113x over previous
//
#include <hip/hip_runtime.h>

#define EPS   1e-5f
#define NB    16
#define NS    2048
#define ND    768
#define NK    64
#define NPB   (NS * ND)      /* 1572864 elems per batch */

typedef __attribute__((ext_vector_type(8))) short short8;
typedef __attribute__((ext_vector_type(4))) float f32x4;

static __device__ __forceinline__ short f2bf(float f) {
    unsigned u = __builtin_bit_cast(unsigned, f);
    u += 0x7fffu + ((u >> 16) & 1u);   // round-to-nearest-even
    return (short)(u >> 16);
}

// ---------------------------------------------------------------------------
// Kernel 1: per-batch partial sums (NO atomics) + weight prep.
//   blocks [0,1024):    per-(batch,chunk) {sum,sumsq}; per-WAVE partial ->
//                       plain store to stats_p[bid*4+wid] (4096 distinct slots)
//   blocks [1024,1088): wdp[k][d] = bf16(W_ln[d]*W_down[k][d]); c1[k], c2[k]
//   blocks [1088,1280): wub = bf16(W_up)
// ---------------------------------------------------------------------------
__global__ __launch_bounds__(256) void prep_reduce(
    const float* __restrict__ x, const float* __restrict__ W_up,
    const float* __restrict__ W_down, const float* __restrict__ W_ln,
    const float* __restrict__ b_ln, float2* __restrict__ stats_p,
    float* __restrict__ c1, float* __restrict__ c2,
    short* __restrict__ wdp, short* __restrict__ wub)
{
    __shared__ float red[8];
    const int bid = blockIdx.x, tid = threadIdx.x;
    const int wid = tid >> 6, lane = tid & 63;

    if (bid < 1024) {
        const int b = bid >> 6;
        const int chunk = bid & 63;
        const f32x4* xv = (const f32x4*)(x + (size_t)b * NPB + (size_t)chunk * (NPB / 64));
        float s = 0.f, ss = 0.f;
        #pragma unroll 8
        for (int i = tid; i < NPB / 64 / 4; i += 256) {
            f32x4 v = xv[i];
            s  += v[0] + v[1] + v[2] + v[3];
            ss += v[0]*v[0] + v[1]*v[1] + v[2]*v[2] + v[3]*v[3];
        }
        #pragma unroll
        for (int off = 32; off > 0; off >>= 1) {
            s  += __shfl_down(s, off, 64);
            ss += __shfl_down(ss, off, 64);
        }
        if (lane == 0) stats_p[bid * 4 + wid] = make_float2(s, ss);
    } else if (bid < 1088) {
        const int k = bid - 1024;
        float pc1 = 0.f, pc2 = 0.f;
        #pragma unroll
        for (int d = tid; d < ND; d += 256) {
            float wl = W_ln[d], wd = W_down[k * ND + d], bl = b_ln[d];
            wdp[k * ND + d] = f2bf(wl * wd);
            pc1 += wl * wd;
            pc2 += bl * wd;
        }
        #pragma unroll
        for (int off = 32; off > 0; off >>= 1) {
            pc1 += __shfl_down(pc1, off, 64);
            pc2 += __shfl_down(pc2, off, 64);
        }
        if (lane == 0) { red[wid] = pc1; red[4 + wid] = pc2; }
        __syncthreads();
        if (tid == 0) c1[k] = red[0] + red[1] + red[2] + red[3];
        if (tid == 1) c2[k] = red[4] + red[5] + red[6] + red[7];
    } else {
        const int i = (bid - 1088) * 256 + tid;   // exactly covers 49152
        wub[i] = f2bf(W_up[i]);
    }
}

// ---------------------------------------------------------------------------
// Kernel 2: fused LN + down-proj + ReLU + up-proj + residual.
// 512 blocks x 256 threads; 4 waves/block; each wave owns 16 rows.
// ---------------------------------------------------------------------------
__global__ __launch_bounds__(256) void fused_main(
    const float* __restrict__ x, const short* __restrict__ wdp,
    const short* __restrict__ wub, const float* __restrict__ c1,
    const float* __restrict__ c2, const float2* __restrict__ stats_p,
    float* __restrict__ out)
{
    __shared__ __align__(16) short h_lds[4][16][64];
    const int tid  = threadIdx.x;
    const int wid  = tid >> 6;
    const int lane = tid & 63;
    const int r    = lane & 15;        // MFMA row (A) / col (B,D)
    const int g    = lane >> 4;        // k-group
    const int row0 = blockIdx.x * 64 + wid * 16;
    const int b    = blockIdx.x >> 5;  // 32 blocks per batch

    // ---- fold the 256 per-wave partials for this batch (L2-hit, no sync) --
    float s = 0.f, ss = 0.f;
    #pragma unroll
    for (int i = 0; i < 4; ++i) {
        float2 sp = stats_p[b * 256 + i * 64 + lane];
        s += sp.x; ss += sp.y;
    }
    #pragma unroll
    for (int off = 32; off > 0; off >>= 1) {
        s  += __shfl_xor(s, off, 64);
        ss += __shfl_xor(ss, off, 64);
    }
    const float invN = 1.f / (float)NPB;
    const float mu  = s * invN;
    const float var = ss * invN - mu * mu;
    const float rs  = rsqrtf(var + EPS);

    // ---- GEMM1: acc[cf] accumulates x-row . wdp[col]  --------------------
    f32x4 acc[4] = {};
    const float* xa = x + (size_t)(row0 + r) * ND;
    #pragma unroll 2
    for (int d0 = 0; d0 < ND; d0 += 32) {
        const int da = d0 + g * 8;
        f32x4 a0 = *(const f32x4*)(xa + da);
        f32x4 a1 = *(const f32x4*)(xa + da + 4);
        short8 af;
        af[0] = f2bf(a0[0]); af[1] = f2bf(a0[1]); af[2] = f2bf(a0[2]); af[3] = f2bf(a0[3]);
        af[4] = f2bf(a1[0]); af[5] = f2bf(a1[1]); af[6] = f2bf(a1[2]); af[7] = f2bf(a1[3]);
        #pragma unroll
        for (int cf = 0; cf < 4; ++cf) {
            short8 bf = *(const short8*)(wdp + (cf * 16 + r) * ND + da);
            acc[cf] = __builtin_amdgcn_mfma_f32_16x16x32_bf16(af, bf, acc[cf], 0, 0, 0);
        }
    }

    // ---- epilogue 1: z = rs*acc + kb[col]; relu; -> h_lds (bf16) ----------
    #pragma unroll
    for (int cf = 0; cf < 4; ++cf) {
        const int col = cf * 16 + r;
        const float kb = c2[col] - rs * mu * c1[col];
        #pragma unroll
        for (int reg = 0; reg < 4; ++reg) {
            float z = fmaf(rs, acc[cf][reg], kb);
            h_lds[wid][g * 4 + reg][col] = f2bf(fmaxf(z, 0.f));
        }
    }
    __syncthreads();

    // ---- GEMM2 A-fragments: full K=64, loaded once ------------------------
    short8 a2_0 = *(const short8*)&h_lds[wid][r][g * 8];
    short8 a2_1 = *(const short8*)&h_lds[wid][r][32 + g * 8];

    const float* xr   = x   + (size_t)row0 * ND;
    float*       outr = out + (size_t)row0 * ND;

    for (int dc = 0; dc < 12; ++dc) {
        f32x4 acc2[4] = {};
        #pragma unroll
        for (int cf = 0; cf < 4; ++cf) {
            const int dcol = dc * 64 + cf * 16 + r;
            short8 b0 = *(const short8*)(wub + dcol * 64 + g * 8);
            short8 b1 = *(const short8*)(wub + dcol * 64 + 32 + g * 8);
            acc2[cf] = __builtin_amdgcn_mfma_f32_16x16x32_bf16(a2_0, b0, acc2[cf], 0, 0, 0);
            acc2[cf] = __builtin_amdgcn_mfma_f32_16x16x32_bf16(a2_1, b1, acc2[cf], 0, 0, 0);
        }
        // ---- epilogue 2: residual add + non-temporal store ----
        #pragma unroll
        for (int cf = 0; cf < 4; ++cf) {
            #pragma unroll
            for (int reg = 0; reg < 4; ++reg) {
                const int row = g * 4 + reg;
                const int col = dc * 64 + cf * 16 + r;
                float v = xr[(size_t)row * ND + col] + acc2[cf][reg];
                __builtin_nontemporal_store(v, &outr[(size_t)row * ND + col]);
            }
        }
    }
}

// ---------------------------------------------------------------------------
extern "C" void kernel_launch(void* const* d_in, const int* in_sizes, int n_in,
                              void* d_out, int out_size, void* d_ws, size_t ws_size,
                              hipStream_t stream)
{
    const float* x      = (const float*)d_in[0];
    const float* W_up   = (const float*)d_in[1];
    // d_in[2] = b_up   (unused by reference)
    const float* W_down = (const float*)d_in[3];
    // d_in[4] = b_down (unused by reference)
    const float* W_ln   = (const float*)d_in[5];
    const float* b_ln   = (const float*)d_in[6];
    float* out = (float*)d_out;

    char* ws = (char*)d_ws;
    float2* stats_p = (float2*)ws;                 // 4096 x float2 = 32 KiB
    float*  c1      = (float*)(ws + 32768);        // 64 f32
    float*  c2      = (float*)(ws + 33024);        // 64 f32
    short*  wdp     = (short*)(ws + 33280);        // bf16 [64][768] = 96 KiB
    short*  wub     = (short*)(ws + 131584);       // bf16 [768][64] = 96 KiB

    prep_reduce<<<1280, 256, 0, stream>>>(x, W_up, W_down, W_ln, b_ln,
                                          stats_p, c1, c2, wdp, wub);
    fused_main<<<512, 256, 0, stream>>>(x, wdp, wub, c1, c2, stats_p, out);
}

// Round 3
// 84.856 us; speedup vs baseline: 1.8225x; 1.0062x over previous
//
#include <hip/hip_runtime.h>

#define EPS   1e-5f
#define NB    16
#define NS    2048
#define ND    768
#define NK    64
#define NPB   (NS * ND)      /* 1572864 elems per batch */

typedef __attribute__((ext_vector_type(8))) short short8;
typedef __attribute__((ext_vector_type(4))) float f32x4;

static __device__ __forceinline__ short f2bf(float f) {
    unsigned u = __builtin_bit_cast(unsigned, f);
    u += 0x7fffu + ((u >> 16) & 1u);   // round-to-nearest-even
    return (short)(u >> 16);
}

// ---------------------------------------------------------------------------
// Kernel 1: per-batch partial sums (NO atomics) + weight prep.
// ---------------------------------------------------------------------------
__global__ __launch_bounds__(256) void prep_reduce(
    const float* __restrict__ x, const float* __restrict__ W_up,
    const float* __restrict__ W_down, const float* __restrict__ W_ln,
    const float* __restrict__ b_ln, float2* __restrict__ stats_p,
    float* __restrict__ c1, float* __restrict__ c2,
    short* __restrict__ wdp, short* __restrict__ wub)
{
    __shared__ float red[8];
    const int bid = blockIdx.x, tid = threadIdx.x;
    const int wid = tid >> 6, lane = tid & 63;

    if (bid < 1024) {
        const int b = bid >> 6;
        const int chunk = bid & 63;
        const f32x4* xv = (const f32x4*)(x + (size_t)b * NPB + (size_t)chunk * (NPB / 64));
        float s = 0.f, ss = 0.f;
        #pragma unroll 8
        for (int i = tid; i < NPB / 64 / 4; i += 256) {
            f32x4 v = xv[i];
            s  += v[0] + v[1] + v[2] + v[3];
            ss += v[0]*v[0] + v[1]*v[1] + v[2]*v[2] + v[3]*v[3];
        }
        #pragma unroll
        for (int off = 32; off > 0; off >>= 1) {
            s  += __shfl_down(s, off, 64);
            ss += __shfl_down(ss, off, 64);
        }
        if (lane == 0) stats_p[bid * 4 + wid] = make_float2(s, ss);
    } else if (bid < 1088) {
        const int k = bid - 1024;
        float pc1 = 0.f, pc2 = 0.f;
        #pragma unroll
        for (int d = tid; d < ND; d += 256) {
            float wl = W_ln[d], wd = W_down[k * ND + d], bl = b_ln[d];
            wdp[k * ND + d] = f2bf(wl * wd);
            pc1 += wl * wd;
            pc2 += bl * wd;
        }
        #pragma unroll
        for (int off = 32; off > 0; off >>= 1) {
            pc1 += __shfl_down(pc1, off, 64);
            pc2 += __shfl_down(pc2, off, 64);
        }
        if (lane == 0) { red[wid] = pc1; red[4 + wid] = pc2; }
        __syncthreads();
        if (tid == 0) c1[k] = red[0] + red[1] + red[2] + red[3];
        if (tid == 1) c2[k] = red[4] + red[5] + red[6] + red[7];
    } else {
        const int i = (bid - 1088) * 256 + tid;   // exactly covers 49152
        wub[i] = f2bf(W_up[i]);
    }
}

// ---------------------------------------------------------------------------
// Kernel 2: fused LN + down-proj + ReLU + up-proj + residual.
// 1024 blocks x 256 threads (4 waves). Block owns 32 rows.
// Wave = (sub = wid&1 -> which 16-row group, half = wid>>1 -> D-half).
// GEMM1: each wave reduces its 384-wide D-half (12 k-steps); half-1 parks
// f32 partials in LDS; half-0 combines + LN-affine + ReLU -> h_lds (bf16).
// GEMM2: halves split the 12 output column-chunks 6/6.
// ---------------------------------------------------------------------------
__global__ __launch_bounds__(256) void fused_main(
    const float* __restrict__ x, const short* __restrict__ wdp,
    const short* __restrict__ wub, const float* __restrict__ c1,
    const float* __restrict__ c2, const float2* __restrict__ stats_p,
    float* __restrict__ out)
{
    __shared__ __align__(16) float pacc[2][64][16];   // 8 KiB  (half-1 partials)
    __shared__ __align__(16) short h_lds[2][16][64];  // 4 KiB
    const int tid  = threadIdx.x;
    const int wid  = tid >> 6;
    const int lane = tid & 63;
    const int sub  = wid & 1;          // 16-row group within block
    const int half = wid >> 1;         // D-half for GEMM1 / chunk-half for GEMM2
    const int r    = lane & 15;        // MFMA row (A) / col (B,D)
    const int g    = lane >> 4;        // k-group
    const int row0 = blockIdx.x * 32 + sub * 16;
    const int b    = blockIdx.x >> 6;  // 64 blocks per batch

    // ---- fold the 256 per-wave partials for this batch (L2-hit) ----------
    float s = 0.f, ss = 0.f;
    #pragma unroll
    for (int i = 0; i < 4; ++i) {
        float2 sp = stats_p[b * 256 + i * 64 + lane];
        s += sp.x; ss += sp.y;
    }
    #pragma unroll
    for (int off = 32; off > 0; off >>= 1) {
        s  += __shfl_xor(s, off, 64);
        ss += __shfl_xor(ss, off, 64);
    }
    const float invN = 1.f / (float)NPB;
    const float mu  = s * invN;
    const float var = ss * invN - mu * mu;
    const float rs  = rsqrtf(var + EPS);

    // ---- GEMM1 over this wave's D-half (12 k-steps, reg double-buffer) ----
    f32x4 acc[4] = {};
    const float* xa  = x + (size_t)(row0 + r) * ND + half * 384;
    const short* wdh = wdp + half * 384;
    f32x4 a0 = *(const f32x4*)(xa + g * 8);
    f32x4 a1 = *(const f32x4*)(xa + g * 8 + 4);
    for (int kk = 0; kk < 12; ++kk) {
        f32x4 n0, n1;
        if (kk < 11) {
            n0 = *(const f32x4*)(xa + (kk + 1) * 32 + g * 8);
            n1 = *(const f32x4*)(xa + (kk + 1) * 32 + g * 8 + 4);
        }
        short8 af;
        af[0] = f2bf(a0[0]); af[1] = f2bf(a0[1]); af[2] = f2bf(a0[2]); af[3] = f2bf(a0[3]);
        af[4] = f2bf(a1[0]); af[5] = f2bf(a1[1]); af[6] = f2bf(a1[2]); af[7] = f2bf(a1[3]);
        #pragma unroll
        for (int cf = 0; cf < 4; ++cf) {
            short8 bf = *(const short8*)(wdh + (cf * 16 + r) * ND + kk * 32 + g * 8);
            acc[cf] = __builtin_amdgcn_mfma_f32_16x16x32_bf16(af, bf, acc[cf], 0, 0, 0);
        }
        a0 = n0; a1 = n1;
    }

    // ---- combine halves; LN affine + ReLU -> h_lds (bf16) -----------------
    if (half == 1) {
        #pragma unroll
        for (int cf = 0; cf < 4; ++cf)
            *(f32x4*)&pacc[sub][lane][cf * 4] = acc[cf];
    }
    __syncthreads();
    if (half == 0) {
        #pragma unroll
        for (int cf = 0; cf < 4; ++cf) {
            f32x4 other = *(const f32x4*)&pacc[sub][lane][cf * 4];
            const int col = cf * 16 + r;
            const float kb = c2[col] - rs * mu * c1[col];
            #pragma unroll
            for (int reg = 0; reg < 4; ++reg) {
                float z = fmaf(rs, acc[cf][reg] + other[reg], kb);
                h_lds[sub][g * 4 + reg][col] = f2bf(fmaxf(z, 0.f));
            }
        }
    }
    __syncthreads();

    // ---- GEMM2: this wave handles 6 of 12 column-chunks -------------------
    short8 a2_0 = *(const short8*)&h_lds[sub][r][g * 8];
    short8 a2_1 = *(const short8*)&h_lds[sub][r][32 + g * 8];

    const float* xr   = x   + (size_t)row0 * ND;
    float*       outr = out + (size_t)row0 * ND;

    for (int dcl = 0; dcl < 6; ++dcl) {
        const int dc = half * 6 + dcl;
        f32x4 acc2[4] = {};
        #pragma unroll
        for (int cf = 0; cf < 4; ++cf) {
            const int dcol = dc * 64 + cf * 16 + r;
            short8 b0 = *(const short8*)(wub + dcol * 64 + g * 8);
            short8 b1 = *(const short8*)(wub + dcol * 64 + 32 + g * 8);
            acc2[cf] = __builtin_amdgcn_mfma_f32_16x16x32_bf16(a2_0, b0, acc2[cf], 0, 0, 0);
            acc2[cf] = __builtin_amdgcn_mfma_f32_16x16x32_bf16(a2_1, b1, acc2[cf], 0, 0, 0);
        }
        #pragma unroll
        for (int cf = 0; cf < 4; ++cf) {
            #pragma unroll
            for (int reg = 0; reg < 4; ++reg) {
                const int row = g * 4 + reg;
                const int col = dc * 64 + cf * 16 + r;
                float v = xr[(size_t)row * ND + col] + acc2[cf][reg];
                __builtin_nontemporal_store(v, &outr[(size_t)row * ND + col]);
            }
        }
    }
}

// ---------------------------------------------------------------------------
extern "C" void kernel_launch(void* const* d_in, const int* in_sizes, int n_in,
                              void* d_out, int out_size, void* d_ws, size_t ws_size,
                              hipStream_t stream)
{
    const float* x      = (const float*)d_in[0];
    const float* W_up   = (const float*)d_in[1];
    // d_in[2] = b_up   (unused by reference)
    const float* W_down = (const float*)d_in[3];
    // d_in[4] = b_down (unused by reference)
    const float* W_ln   = (const float*)d_in[5];
    const float* b_ln   = (const float*)d_in[6];
    float* out = (float*)d_out;

    char* ws = (char*)d_ws;
    float2* stats_p = (float2*)ws;                 // 4096 x float2 = 32 KiB
    float*  c1      = (float*)(ws + 32768);        // 64 f32
    float*  c2      = (float*)(ws + 33024);        // 64 f32
    short*  wdp     = (short*)(ws + 33280);        // bf16 [64][768] = 96 KiB
    short*  wub     = (short*)(ws + 131584);       // bf16 [768][64] = 96 KiB

    prep_reduce<<<1280, 256, 0, stream>>>(x, W_up, W_down, W_ln, b_ln,
                                          stats_p, c1, c2, wdp, wub);
    fused_main<<<1024, 256, 0, stream>>>(x, wdp, wub, c1, c2, stats_p, out);
}

// Round 4
// 74.335 us; speedup vs baseline: 2.0805x; 1.1415x over previous
//
#include <hip/hip_runtime.h>

#define EPS   1e-5f
#define NB    16
#define NS    2048
#define ND    768
#define NK    64
#define NPB   (NS * ND)      /* 1572864 elems per batch */

typedef __attribute__((ext_vector_type(8))) short short8;
typedef __attribute__((ext_vector_type(4))) float f32x4;

static __device__ __forceinline__ short f2bf(float f) {
    unsigned u = __builtin_bit_cast(unsigned, f);
    u += 0x7fffu + ((u >> 16) & 1u);   // round-to-nearest-even
    return (short)(u >> 16);
}

// ---------------------------------------------------------------------------
// Kernel 1: per-batch partial sums (NO atomics) + weight prep.
// ---------------------------------------------------------------------------
__global__ __launch_bounds__(256) void prep_reduce(
    const float* __restrict__ x, const float* __restrict__ W_up,
    const float* __restrict__ W_down, const float* __restrict__ W_ln,
    const float* __restrict__ b_ln, float2* __restrict__ stats_p,
    float* __restrict__ c1, float* __restrict__ c2,
    short* __restrict__ wdp, short* __restrict__ wub)
{
    __shared__ float red[8];
    const int bid = blockIdx.x, tid = threadIdx.x;
    const int wid = tid >> 6, lane = tid & 63;

    if (bid < 1024) {
        const int b = bid >> 6;
        const int chunk = bid & 63;
        const f32x4* xv = (const f32x4*)(x + (size_t)b * NPB + (size_t)chunk * (NPB / 64));
        float s = 0.f, ss = 0.f;
        #pragma unroll 8
        for (int i = tid; i < NPB / 64 / 4; i += 256) {
            f32x4 v = xv[i];
            s  += v[0] + v[1] + v[2] + v[3];
            ss += v[0]*v[0] + v[1]*v[1] + v[2]*v[2] + v[3]*v[3];
        }
        #pragma unroll
        for (int off = 32; off > 0; off >>= 1) {
            s  += __shfl_down(s, off, 64);
            ss += __shfl_down(ss, off, 64);
        }
        if (lane == 0) stats_p[bid * 4 + wid] = make_float2(s, ss);
    } else if (bid < 1088) {
        const int k = bid - 1024;
        float pc1 = 0.f, pc2 = 0.f;
        #pragma unroll
        for (int d = tid; d < ND; d += 256) {
            float wl = W_ln[d], wd = W_down[k * ND + d], bl = b_ln[d];
            wdp[k * ND + d] = f2bf(wl * wd);
            pc1 += wl * wd;
            pc2 += bl * wd;
        }
        #pragma unroll
        for (int off = 32; off > 0; off >>= 1) {
            pc1 += __shfl_down(pc1, off, 64);
            pc2 += __shfl_down(pc2, off, 64);
        }
        if (lane == 0) { red[wid] = pc1; red[4 + wid] = pc2; }
        __syncthreads();
        if (tid == 0) c1[k] = red[0] + red[1] + red[2] + red[3];
        if (tid == 1) c2[k] = red[4] + red[5] + red[6] + red[7];
    } else {
        const int i = (bid - 1088) * 256 + tid;   // exactly covers 49152
        wub[i] = f2bf(W_up[i]);
    }
}

// ---------------------------------------------------------------------------
// Kernel 2: fused LN + down-proj + ReLU + up-proj + residual.
// 512 blocks x 256 threads (4 waves); block = 64 rows; wave = 16 rows.
// Weights LDS-staged per block (dense coalesced loads, XOR-swizzled rows);
// epilogue vectorized via per-wave LDS transpose -> float4 loads/stores.
// ---------------------------------------------------------------------------
__global__ __launch_bounds__(256) void fused_main(
    const float* __restrict__ x, const short* __restrict__ wdp,
    const short* __restrict__ wub, const float* __restrict__ c1,
    const float* __restrict__ c2, const float2* __restrict__ stats_p,
    float* __restrict__ out)
{
    __shared__ __align__(16) char  wbuf[49152];      // weight staging (dbuf, reused G1/G2)
    __shared__ __align__(16) short h_lds[4][1024];   // per-wave 16x64 bf16, swizzled 128B rows
    __shared__ __align__(16) float stg[4][1088];     // per-wave 16x68 f32 transpose buffer

    const int tid  = threadIdx.x;
    const int wid  = tid >> 6;
    const int lane = tid & 63;
    const int r    = lane & 15;        // MFMA row (A) / col (B,D)
    const int g    = lane >> 4;        // k-group
    const int sw   = (r & 7) << 4;     // read-side XOR swizzle
    const int row0 = blockIdx.x * 64 + wid * 16;
    const int b    = blockIdx.x >> 5;  // 32 blocks per batch

    // ---- fold the 256 per-wave partials for this batch (L2-hit) ----------
    float s = 0.f, ss = 0.f;
    #pragma unroll
    for (int i = 0; i < 4; ++i) {
        float2 sp = stats_p[b * 256 + i * 64 + lane];
        s += sp.x; ss += sp.y;
    }
    #pragma unroll
    for (int off = 32; off > 0; off >>= 1) {
        s  += __shfl_xor(s, off, 64);
        ss += __shfl_xor(ss, off, 64);
    }
    const float invN = 1.f / (float)NPB;
    const float mu  = s * invN;
    const float var = ss * invN - mu * mu;
    const float rs  = rsqrtf(var + EPS);

    // ---- staging helpers (reg-staged, XOR-swizzled LDS rows) --------------
    auto stage_wdp = [&](int c, int p) {   // chunk c: wdp[:, c*192 .. +192) -> 64 rows x 384B
        char* dst = wbuf + p * 24576;
        #pragma unroll
        for (int i = 0; i < 6; ++i) {
            int idx = i * 256 + tid;               // 16B units, [0,1536)
            int row = idx / 24, u = idx % 24;
            short8 v = *(const short8*)(wdp + row * ND + c * 192 + u * 8);
            *(short8*)(dst + row * 384 + ((u * 16) ^ ((row & 7) << 4))) = v;
        }
    };
    auto stage_wub = [&](int w, int p) {   // chunk w: wub rows [w*128, +128) -> 128 rows x 128B
        char* dst = wbuf + p * 16384;
        #pragma unroll
        for (int i = 0; i < 4; ++i) {
            int idx = i * 256 + tid;               // 16B units, [0,1024)
            int row = idx >> 3, u = idx & 7;
            short8 v = *(const short8*)(wub + (w * 128 + row) * 64 + u * 8);
            *(short8*)(dst + row * 128 + ((u * 16) ^ ((row & 7) << 4))) = v;
        }
    };

    // ---- GEMM1: acc += bf16(x-row) . staged-wdp, 4 d-chunks of 192 --------
    f32x4 acc[4] = {};
    auto compute_g1 = [&](int p, int c) {
        const char* B = wbuf + p * 24576;
        const float* xa = x + (size_t)(row0 + r) * ND + c * 192 + g * 8;
        #pragma unroll
        for (int kk = 0; kk < 6; ++kk) {
            f32x4 a0 = *(const f32x4*)(xa + kk * 32);
            f32x4 a1 = *(const f32x4*)(xa + kk * 32 + 4);
            short8 af;
            af[0] = f2bf(a0[0]); af[1] = f2bf(a0[1]); af[2] = f2bf(a0[2]); af[3] = f2bf(a0[3]);
            af[4] = f2bf(a1[0]); af[5] = f2bf(a1[1]); af[6] = f2bf(a1[2]); af[7] = f2bf(a1[3]);
            #pragma unroll
            for (int cf = 0; cf < 4; ++cf) {
                short8 bf = *(const short8*)(B + (cf * 16 + r) * 384
                                               + ((kk * 64 + g * 16) ^ sw));
                acc[cf] = __builtin_amdgcn_mfma_f32_16x16x32_bf16(af, bf, acc[cf], 0, 0, 0);
            }
        }
    };

    stage_wdp(0, 0);                  __syncthreads();
    stage_wdp(1, 1); compute_g1(0, 0); __syncthreads();
    stage_wdp(2, 0); compute_g1(1, 1); __syncthreads();
    stage_wdp(3, 1); compute_g1(0, 2); __syncthreads();
    stage_wub(0, 0); compute_g1(1, 3); __syncthreads();

    // ---- epilogue 1: z = rs*acc + kb; relu; -> own h_lds (swizzled bf16) --
    #pragma unroll
    for (int cf = 0; cf < 4; ++cf) {
        const int col = cf * 16 + r;
        const float kb = c2[col] - rs * mu * c1[col];
        #pragma unroll
        for (int reg = 0; reg < 4; ++reg) {
            float z = fmaf(rs, acc[cf][reg], kb);
            const int hrow = g * 4 + reg;
            *(short*)((char*)h_lds[wid] + hrow * 128
                      + ((col * 2) ^ ((hrow & 7) << 4))) = f2bf(fmaxf(z, 0.f));
        }
    }

    // ---- GEMM2 A-fragments (own wave's h, K=64) ---------------------------
    const char* H = (const char*)h_lds[wid] + r * 128;
    short8 a2_0 = *(const short8*)(H + ((g * 16) ^ sw));
    short8 a2_1 = *(const short8*)(H + ((64 + g * 16) ^ sw));

    const float* xr   = x   + (size_t)row0 * ND;
    float*       outr = out + (size_t)row0 * ND;
    const int rrow = lane >> 2;        // epilogue row 0..15
    const int pq   = lane & 3;
    float* S = stg[wid];

    for (int w = 0; w < 6; ++w) {
        if (w < 5) stage_wub(w + 1, (w + 1) & 1);
        const char* W = wbuf + (w & 1) * 16384;
        #pragma unroll
        for (int dq = 0; dq < 2; ++dq) {
            const int dcg = w * 2 + dq;                    // global 64-col chunk
            f32x4 acc2[4] = {};
            #pragma unroll
            for (int cf = 0; cf < 4; ++cf) {
                const int dl = dq * 64 + cf * 16 + r;      // local wub row
                short8 b0 = *(const short8*)(W + dl * 128 + ((g * 16) ^ sw));
                short8 b1 = *(const short8*)(W + dl * 128 + ((64 + g * 16) ^ sw));
                acc2[cf] = __builtin_amdgcn_mfma_f32_16x16x32_bf16(a2_0, b0, acc2[cf], 0, 0, 0);
                acc2[cf] = __builtin_amdgcn_mfma_f32_16x16x32_bf16(a2_1, b1, acc2[cf], 0, 0, 0);
            }
            // transpose C/D layout -> row-major via per-wave LDS
            #pragma unroll
            for (int cf = 0; cf < 4; ++cf)
                #pragma unroll
                for (int reg = 0; reg < 4; ++reg)
                    S[(g * 4 + reg) * 68 + cf * 16 + r] = acc2[cf][reg];
            // float4 residual add + nontemporal float4 store
            #pragma unroll
            for (int j = 0; j < 4; ++j) {
                f32x4 v  = *(const f32x4*)(S + rrow * 68 + j * 16 + pq * 4);
                const int col = dcg * 64 + j * 16 + pq * 4;
                f32x4 xv = *(const f32x4*)(xr + (size_t)rrow * ND + col);
                v[0] += xv[0]; v[1] += xv[1]; v[2] += xv[2]; v[3] += xv[3];
                __builtin_nontemporal_store(v[0], &outr[(size_t)rrow * ND + col]);
                __builtin_nontemporal_store(v[1], &outr[(size_t)rrow * ND + col + 1]);
                __builtin_nontemporal_store(v[2], &outr[(size_t)rrow * ND + col + 2]);
                __builtin_nontemporal_store(v[3], &outr[(size_t)rrow * ND + col + 3]);
            }
        }
        __syncthreads();
    }
}

// ---------------------------------------------------------------------------
extern "C" void kernel_launch(void* const* d_in, const int* in_sizes, int n_in,
                              void* d_out, int out_size, void* d_ws, size_t ws_size,
                              hipStream_t stream)
{
    const float* x      = (const float*)d_in[0];
    const float* W_up   = (const float*)d_in[1];
    // d_in[2] = b_up   (unused by reference)
    const float* W_down = (const float*)d_in[3];
    // d_in[4] = b_down (unused by reference)
    const float* W_ln   = (const float*)d_in[5];
    const float* b_ln   = (const float*)d_in[6];
    float* out = (float*)d_out;

    char* ws = (char*)d_ws;
    float2* stats_p = (float2*)ws;                 // 4096 x float2 = 32 KiB
    float*  c1      = (float*)(ws + 32768);        // 64 f32
    float*  c2      = (float*)(ws + 33024);        // 64 f32
    short*  wdp     = (short*)(ws + 33280);        // bf16 [64][768] = 96 KiB
    short*  wub     = (short*)(ws + 131584);       // bf16 [768][64] = 96 KiB

    prep_reduce<<<1280, 256, 0, stream>>>(x, W_up, W_down, W_ln, b_ln,
                                          stats_p, c1, c2, wdp, wub);
    fused_main<<<512, 256, 0, stream>>>(x, wdp, wub, c1, c2, stats_p, out);
}

// Round 6
// 65.639 us; speedup vs baseline: 2.3561x; 1.1325x over previous
//
#include <hip/hip_runtime.h>

#define EPS   1e-5f
#define NB    16
#define NS    2048
#define ND    768
#define NK    64
#define NPB   (NS * ND)      /* 1572864 elems per batch */

typedef __attribute__((ext_vector_type(8))) short short8;
typedef __attribute__((ext_vector_type(4))) float f32x4;

static __device__ __forceinline__ short f2bf(float f) {
    unsigned u = __builtin_bit_cast(unsigned, f);
    u += 0x7fffu + ((u >> 16) & 1u);   // round-to-nearest-even
    return (short)(u >> 16);
}

// ---------------------------------------------------------------------------
// Kernel 1: per-batch partial sums (NO atomics) + weight prep.  (unchanged)
// ---------------------------------------------------------------------------
__global__ __launch_bounds__(256) void prep_reduce(
    const float* __restrict__ x, const float* __restrict__ W_up,
    const float* __restrict__ W_down, const float* __restrict__ W_ln,
    const float* __restrict__ b_ln, float2* __restrict__ stats_p,
    float* __restrict__ c1, float* __restrict__ c2,
    short* __restrict__ wdp, short* __restrict__ wub)
{
    __shared__ float red[8];
    const int bid = blockIdx.x, tid = threadIdx.x;
    const int wid = tid >> 6, lane = tid & 63;

    if (bid < 1024) {
        const int b = bid >> 6;
        const int chunk = bid & 63;
        const f32x4* xv = (const f32x4*)(x + (size_t)b * NPB + (size_t)chunk * (NPB / 64));
        float s = 0.f, ss = 0.f;
        #pragma unroll 8
        for (int i = tid; i < NPB / 64 / 4; i += 256) {
            f32x4 v = xv[i];
            s  += v[0] + v[1] + v[2] + v[3];
            ss += v[0]*v[0] + v[1]*v[1] + v[2]*v[2] + v[3]*v[3];
        }
        #pragma unroll
        for (int off = 32; off > 0; off >>= 1) {
            s  += __shfl_down(s, off, 64);
            ss += __shfl_down(ss, off, 64);
        }
        if (lane == 0) stats_p[bid * 4 + wid] = make_float2(s, ss);
    } else if (bid < 1088) {
        const int k = bid - 1024;
        float pc1 = 0.f, pc2 = 0.f;
        #pragma unroll
        for (int d = tid; d < ND; d += 256) {
            float wl = W_ln[d], wd = W_down[k * ND + d], bl = b_ln[d];
            wdp[k * ND + d] = f2bf(wl * wd);
            pc1 += wl * wd;
            pc2 += bl * wd;
        }
        #pragma unroll
        for (int off = 32; off > 0; off >>= 1) {
            pc1 += __shfl_down(pc1, off, 64);
            pc2 += __shfl_down(pc2, off, 64);
        }
        if (lane == 0) { red[wid] = pc1; red[4 + wid] = pc2; }
        __syncthreads();
        if (tid == 0) c1[k] = red[0] + red[1] + red[2] + red[3];
        if (tid == 1) c2[k] = red[4] + red[5] + red[6] + red[7];
    } else {
        const int i = (bid - 1088) * 256 + tid;   // exactly covers 49152
        wub[i] = f2bf(W_up[i]);
    }
}

// ---------------------------------------------------------------------------
// Kernel 2: fused LN + down-proj + ReLU + up-proj + residual.
// R4 structure (passing) with ONE change: full-line vectorized epilogue.
// 512 blocks x 256 threads (4 waves); block = 64 rows; wave = 16 rows.
// ---------------------------------------------------------------------------
__global__ __launch_bounds__(256) void fused_main(
    const float* __restrict__ x, const short* __restrict__ wdp,
    const short* __restrict__ wub, const float* __restrict__ c1,
    const float* __restrict__ c2, const float2* __restrict__ stats_p,
    float* __restrict__ out)
{
    __shared__ __align__(16) char  wbuf[49152];      // weight staging (dbuf, reused G1/G2)
    __shared__ __align__(16) short h_lds[4][1024];   // per-wave 16x64 bf16, swizzled 128B rows
    __shared__ __align__(16) float stg[4][1088];     // per-wave 16x68 f32 transpose buffer

    const int tid  = threadIdx.x;
    const int wid  = tid >> 6;
    const int lane = tid & 63;
    const int r    = lane & 15;        // MFMA row (A) / col (B,D)
    const int g    = lane >> 4;        // k-group
    const int sw   = (r & 7) << 4;     // read-side XOR swizzle
    const int row0 = blockIdx.x * 64 + wid * 16;
    const int b    = blockIdx.x >> 5;  // 32 blocks per batch

    // ---- fold the 256 per-wave partials for this batch (L2-hit) ----------
    float s = 0.f, ss = 0.f;
    #pragma unroll
    for (int i = 0; i < 4; ++i) {
        float2 sp = stats_p[b * 256 + i * 64 + lane];
        s += sp.x; ss += sp.y;
    }
    #pragma unroll
    for (int off = 32; off > 0; off >>= 1) {
        s  += __shfl_xor(s, off, 64);
        ss += __shfl_xor(ss, off, 64);
    }
    const float invN = 1.f / (float)NPB;
    const float mu  = s * invN;
    const float var = ss * invN - mu * mu;
    const float rs  = rsqrtf(var + EPS);

    // ---- staging helpers (reg-staged, XOR-swizzled LDS rows) --------------
    auto stage_wdp = [&](int c, int p) {   // chunk c: wdp[:, c*192 .. +192) -> 64 rows x 384B
        char* dst = wbuf + p * 24576;
        #pragma unroll
        for (int i = 0; i < 6; ++i) {
            int idx = i * 256 + tid;               // 16B units, [0,1536)
            int row = idx / 24, u = idx % 24;
            short8 v = *(const short8*)(wdp + row * ND + c * 192 + u * 8);
            *(short8*)(dst + row * 384 + ((u * 16) ^ ((row & 7) << 4))) = v;
        }
    };
    auto stage_wub = [&](int w, int p) {   // chunk w: wub rows [w*128, +128) -> 128 rows x 128B
        char* dst = wbuf + p * 16384;
        #pragma unroll
        for (int i = 0; i < 4; ++i) {
            int idx = i * 256 + tid;               // 16B units, [0,1024)
            int row = idx >> 3, u = idx & 7;
            short8 v = *(const short8*)(wub + (w * 128 + row) * 64 + u * 8);
            *(short8*)(dst + row * 128 + ((u * 16) ^ ((row & 7) << 4))) = v;
        }
    };

    // ---- GEMM1: acc += bf16(x-row) . staged-wdp, 4 d-chunks of 192 --------
    f32x4 acc[4] = {};
    auto compute_g1 = [&](int p, int c) {
        const char* B = wbuf + p * 24576;
        const float* xa = x + (size_t)(row0 + r) * ND + c * 192 + g * 8;
        #pragma unroll
        for (int kk = 0; kk < 6; ++kk) {
            f32x4 a0 = *(const f32x4*)(xa + kk * 32);
            f32x4 a1 = *(const f32x4*)(xa + kk * 32 + 4);
            short8 af;
            af[0] = f2bf(a0[0]); af[1] = f2bf(a0[1]); af[2] = f2bf(a0[2]); af[3] = f2bf(a0[3]);
            af[4] = f2bf(a1[0]); af[5] = f2bf(a1[1]); af[6] = f2bf(a1[2]); af[7] = f2bf(a1[3]);
            #pragma unroll
            for (int cf = 0; cf < 4; ++cf) {
                short8 bf = *(const short8*)(B + (cf * 16 + r) * 384
                                               + ((kk * 64 + g * 16) ^ sw));
                acc[cf] = __builtin_amdgcn_mfma_f32_16x16x32_bf16(af, bf, acc[cf], 0, 0, 0);
            }
        }
    };

    stage_wdp(0, 0);                  __syncthreads();
    stage_wdp(1, 1); compute_g1(0, 0); __syncthreads();
    stage_wdp(2, 0); compute_g1(1, 1); __syncthreads();
    stage_wdp(3, 1); compute_g1(0, 2); __syncthreads();
    stage_wub(0, 0); compute_g1(1, 3); __syncthreads();

    // ---- epilogue 1: z = rs*acc + kb; relu; -> own h_lds (swizzled bf16) --
    #pragma unroll
    for (int cf = 0; cf < 4; ++cf) {
        const int col = cf * 16 + r;
        const float kb = c2[col] - rs * mu * c1[col];
        #pragma unroll
        for (int reg = 0; reg < 4; ++reg) {
            float z = fmaf(rs, acc[cf][reg], kb);
            const int hrow = g * 4 + reg;
            *(short*)((char*)h_lds[wid] + hrow * 128
                      + ((col * 2) ^ ((hrow & 7) << 4))) = f2bf(fmaxf(z, 0.f));
        }
    }

    // ---- GEMM2 A-fragments (own wave's h, K=64) ---------------------------
    const char* H = (const char*)h_lds[wid] + r * 128;
    short8 a2_0 = *(const short8*)(H + ((g * 16) ^ sw));
    short8 a2_1 = *(const short8*)(H + ((64 + g * 16) ^ sw));

    const float* xr   = x   + (size_t)row0 * ND;
    float*       outr = out + (size_t)row0 * ND;
    const int erow = lane >> 4;        // 0..3   (full-line epilogue mapping)
    const int ecol = (lane & 15) * 4;  // 0..60
    float* S = stg[wid];

    for (int w = 0; w < 6; ++w) {
        if (w < 5) stage_wub(w + 1, (w + 1) & 1);
        const char* W = wbuf + (w & 1) * 16384;
        #pragma unroll
        for (int dq = 0; dq < 2; ++dq) {
            const int dcg = w * 2 + dq;                    // global 64-col chunk
            f32x4 acc2[4] = {};
            #pragma unroll
            for (int cf = 0; cf < 4; ++cf) {
                const int dl = dq * 64 + cf * 16 + r;      // local wub row
                short8 b0 = *(const short8*)(W + dl * 128 + ((g * 16) ^ sw));
                short8 b1 = *(const short8*)(W + dl * 128 + ((64 + g * 16) ^ sw));
                acc2[cf] = __builtin_amdgcn_mfma_f32_16x16x32_bf16(a2_0, b0, acc2[cf], 0, 0, 0);
                acc2[cf] = __builtin_amdgcn_mfma_f32_16x16x32_bf16(a2_1, b1, acc2[cf], 0, 0, 0);
            }
            // transpose C/D layout -> row-major via per-wave LDS (stride 68)
            #pragma unroll
            for (int cf = 0; cf < 4; ++cf)
                #pragma unroll
                for (int reg = 0; reg < 4; ++reg)
                    S[(g * 4 + reg) * 68 + cf * 16 + r] = acc2[cf][reg];
            // full-line residual add + nt store: 4 rows x 256B per instruction
            #pragma unroll
            for (int j = 0; j < 4; ++j) {
                const int row = j * 4 + erow;
                f32x4 v  = *(const f32x4*)(S + row * 68 + ecol);
                const int col = dcg * 64 + ecol;
                f32x4 xv = *(const f32x4*)(xr + (size_t)row * ND + col);
                v[0] += xv[0]; v[1] += xv[1]; v[2] += xv[2]; v[3] += xv[3];
                __builtin_nontemporal_store(v[0], &outr[(size_t)row * ND + col]);
                __builtin_nontemporal_store(v[1], &outr[(size_t)row * ND + col + 1]);
                __builtin_nontemporal_store(v[2], &outr[(size_t)row * ND + col + 2]);
                __builtin_nontemporal_store(v[3], &outr[(size_t)row * ND + col + 3]);
            }
        }
        __syncthreads();
    }
}

// ---------------------------------------------------------------------------
extern "C" void kernel_launch(void* const* d_in, const int* in_sizes, int n_in,
                              void* d_out, int out_size, void* d_ws, size_t ws_size,
                              hipStream_t stream)
{
    const float* x      = (const float*)d_in[0];
    const float* W_up   = (const float*)d_in[1];
    // d_in[2] = b_up   (unused by reference)
    const float* W_down = (const float*)d_in[3];
    // d_in[4] = b_down (unused by reference)
    const float* W_ln   = (const float*)d_in[5];
    const float* b_ln   = (const float*)d_in[6];
    float* out = (float*)d_out;

    char* ws = (char*)d_ws;
    float2* stats_p = (float2*)ws;                 // 4096 x float2 = 32 KiB
    float*  c1      = (float*)(ws + 32768);        // 64 f32
    float*  c2      = (float*)(ws + 33024);        // 64 f32
    short*  wdp     = (short*)(ws + 33280);        // bf16 [64][768] = 96 KiB
    short*  wub     = (short*)(ws + 131584);       // bf16 [768][64] = 96 KiB

    prep_reduce<<<1280, 256, 0, stream>>>(x, W_up, W_down, W_ln, b_ln,
                                          stats_p, c1, c2, wdp, wub);
    fused_main<<<512, 256, 0, stream>>>(x, wdp, wub, c1, c2, stats_p, out);
}